// Round 16
// baseline (220.010 us; speedup 1.0000x reference)
//
#include <hip/hip_runtime.h>

#define Bb 16
#define Tt 12
#define Nn 1024
#define FIN 32
#define FOUT 64
#define KC 3
#define TF (Tt * FIN)    // 384  — (t,f) fused dim
#define NO (Tt * FOUT)   // 768

#define BM 128
#define BN 192
#define BK 32
#define NKT (Nn / BK)    // 32 K-tiles (K = j = 1024)

typedef __attribute__((ext_vector_type(8))) short short8;
typedef __attribute__((ext_vector_type(4))) float f32x4;

__device__ __forceinline__ unsigned short f2bf(float f) {
  union { float f; unsigned u; } v; v.f = f;
  unsigned r = v.u + 0x7FFFu + ((v.u >> 16) & 1u);  // RNE
  return (unsigned short)(r >> 16);
}

__device__ __forceinline__ unsigned cvtpk(float lo, float hi) {
  unsigned r;
  asm("v_cvt_pk_bf16_f32 %0, %1, %2" : "=v"(r) : "v"(lo), "v"(hi));
  return r;
}

__device__ __forceinline__ void BAR() {
  __builtin_amdgcn_sched_barrier(0);
  __builtin_amdgcn_s_barrier();
  __builtin_amdgcn_sched_barrier(0);
}

// ---------------------------------------------------------------------------
// k2r: YxT[b][t*32+f][j] = bf16(x[b,t,j,f]) — LDS-tiled transpose. (UNCHANGED)
// ---------------------------------------------------------------------------
__global__ __launch_bounds__(256) void k2r_build_YxT(
    const float* __restrict__ x, unsigned short* __restrict__ YxT) {
  __shared__ float xs[256][33];   // +1 pad
  const int tid = threadIdx.x;
  const int bid = blockIdx.x;     // (b*12 + t)*4 + jc
  const int jc = bid & 3;
  const int bt = bid >> 2;
  const int t = bt % Tt, b = bt / Tt;
  const int j0 = jc * 256;
  const float* xp = x + ((size_t)(b * Tt + t) * Nn + j0) * FIN;
#pragma unroll
  for (int m = 0; m < 8; ++m) {
    const int flat = m * 256 + tid;        // 0..2047 float4s
    const int j_loc = flat >> 3, f4 = flat & 7;
    const float4 v = *(const float4*)(xp + (size_t)j_loc * FIN + f4 * 4);
    xs[j_loc][f4 * 4 + 0] = v.x; xs[j_loc][f4 * 4 + 1] = v.y;
    xs[j_loc][f4 * 4 + 2] = v.z; xs[j_loc][f4 * 4 + 3] = v.w;
  }
  __syncthreads();
  const int f = tid >> 3, jg = tid & 7;    // 32 f-rows × 8 j-groups
  unsigned short* dst = YxT + ((size_t)b * TF + t * FIN + f) * Nn + j0 + jg * 32;
#pragma unroll
  for (int m = 0; m < 4; ++m) {
    short8 sh;
#pragma unroll
    for (int e = 0; e < 8; ++e)
      sh[e] = (short)f2bf(xs[jg * 32 + m * 8 + e][f]);
    *(short8*)(dst + m * 8) = sh;
  }
}

// ---------------------------------------------------------------------------
// k3f: FUSED A-build + GEMM. R16: BK=32, 3 blocks/CU (LDS padded to 48 KB so
// exactly 3 fit -> all 768 blocks resident, single round — m97's occupancy
// regime; cross-block overlap absorbs the barrier stalls R4-R15 couldn't).
// Swizzle key for 64-B rows: (row>>1)&3 (2-way bank aliasing = free, m136);
// same involution on BDMA source, CVTW write, LDA/LDB read (rule #21).
// Ledger at wait(tau): {BDMA(tau+1)<=2 old, ISSUE(tau+2)=4 new} -> vmcnt(4)
// for tau<=NKT-4; full drain in tail (incl. tau=30 edge where counted breaks).
// ---------------------------------------------------------------------------
__global__ __launch_bounds__(512, 6) void k3f_gemm(
    const float* __restrict__ att, const float* __restrict__ cheb,
    const unsigned short* __restrict__ YxT, unsigned short* __restrict__ rhs) {
  // used: A 2×4096 + B 2×6144 = 20480 ushorts (40 KB); padded to 48 KB so
  // LDS-occupancy = floor(160/48) = 3 blocks/CU exactly (uniform 3×256=768).
  __shared__ __align__(16) unsigned short lds[24576];
  const int bid = blockIdx.x;
  // 768 blocks; 6 siblings (3kk × 2nt) sharing one (b,it) att panel adjacent
  // on one XCD (R10 grouping, FETCH-verified).
  const int logical = (bid & 7) * 96 + (bid >> 3);   // bijective
  const int g = logical / 6, m = logical % 6;
  const int b  = g >> 3;
  const int it = g & 7;
  const int kk = m >> 1;
  const int nt = m & 1;
  const int bk = b * 3 + kk;
  const float* Aa = att  + ((size_t)b  * Nn + it * BM) * Nn;   // f32 panel
  const float* Ac = cheb + ((size_t)kk * Nn + it * BM) * Nn;   // f32 panel
  const unsigned short* Bp = YxT + ((size_t)b * TF + nt * BN) * Nn;
  const int tid = threadIdx.x;
  const int w = tid >> 6, l = tid & 63;
  const int wm = w >> 2, wn = w & 3;     // 2M × 4N (wave 64×48)
  const int lrow = l & 15;
  const int c0 = l >> 4;                 // k-chunk 0..3 (BK=32 -> 4 chunks)

  f32x4 acc[4][3];
#pragma unroll
  for (int mi = 0; mi < 4; ++mi)
#pragma unroll
    for (int ni = 0; ni < 3; ++ni)
      acc[mi][ni] = (f32x4){0.f, 0.f, 0.f, 0.f};

  float4 ra[2], rc[2];   // single prefetch set (16 VGPR), 1-iter lifetime

  // thread owns row = tid>>2 (0..127), chunk c8 = tid&3 (8 f32 = 32 B)
  const int arow = tid >> 2, ac8 = tid & 3;

  auto ISSUE = [&](int kt) {             // 4 dwordx4 loads -> ra/rc
    const float* ap = Aa + (size_t)arow * Nn + kt * BK + ac8 * 8;
    const float* cp = Ac + (size_t)arow * Nn + kt * BK + ac8 * 8;
    ra[0] = *(const float4*)ap;
    ra[1] = *(const float4*)(ap + 4);
    rc[0] = *(const float4*)cp;
    rc[1] = *(const float4*)(cp + 4);
  };

  auto CVTW = [&](int d) {   // products -> packed bf16 -> one b128 write
    uint4 o;
    o.x = cvtpk(ra[0].x * rc[0].x, ra[0].y * rc[0].y);
    o.y = cvtpk(ra[0].z * rc[0].z, ra[0].w * rc[0].w);
    o.z = cvtpk(ra[1].x * rc[1].x, ra[1].y * rc[1].y);
    o.w = cvtpk(ra[1].z * rc[1].z, ra[1].w * rc[1].w);
    *(uint4*)&lds[d * 4096 + arow * 32 + (ac8 ^ ((arow >> 1) & 3)) * 8] = o;
  };

  auto BDMA = [&](int d, int kt) {       // B: 768 chunks; waves 0-3 do 2nd half
#pragma unroll
    for (int g2 = 0; g2 < 2; ++g2) {
      const int idx = g2 * 512 + tid;    // 0..1023, valid < 768
      if (idx < 768) {
        const int row = idx >> 2;
        const int csrc = (idx & 3) ^ ((row >> 1) & 3);
        __builtin_amdgcn_global_load_lds(
            (const __attribute__((address_space(1))) void*)(Bp + (size_t)row * Nn + kt * BK + csrc * 8),
            (__attribute__((address_space(3))) void*)(lds + 8192 + d * 6144 + (g2 * 512 + w * 64) * 8),
            16, 0, 0);
      }
    }
  };

  auto LDA = [&](int d, int mi) -> short8 {
    const int row = wm * 64 + mi * 16 + lrow;       // 0..127
    const int ch  = c0 ^ ((row >> 1) & 3);
    return *(const short8*)&lds[d * 4096 + row * 32 + ch * 8];
  };
  auto LDB = [&](int d, int ni) -> short8 {
    const int row = wn * 48 + ni * 16 + lrow;       // 0..191
    const int ch  = c0 ^ ((row >> 1) & 3);
    return *(const short8*)&lds[8192 + d * 6144 + row * 32 + ch * 8];
  };

  auto COMPUTE = [&](int d) {
    short8 bf[3];
    __builtin_amdgcn_s_setprio(1);
#pragma unroll
    for (int ni = 0; ni < 3; ++ni) bf[ni] = LDB(d, ni);
#pragma unroll
    for (int mi = 0; mi < 4; ++mi) {
      const short8 af = LDA(d, mi);
#pragma unroll
      for (int ni = 0; ni < 3; ++ni)
        acc[mi][ni] = __builtin_amdgcn_mfma_f32_16x16x32_bf16(af, bf[ni], acc[mi][ni], 0, 0, 0);
    }
    __builtin_amdgcn_s_setprio(0);
  };

  // ---- prologue: A(0),A(1) built; B(0),B(1) DMA'd; ISSUE(2) kept flying ----
  ISSUE(0);
  asm volatile("s_waitcnt vmcnt(0)" ::: "memory");
  CVTW(0);
  ISSUE(1);
  asm volatile("s_waitcnt vmcnt(0)" ::: "memory");
  CVTW(1);
  BDMA(0, 0);
  BDMA(1, 1);
  ISSUE(2);
  asm volatile("s_waitcnt vmcnt(4) lgkmcnt(0)" ::: "memory");  // drain BDMAs+writes, keep ISSUE(2)
  BAR();

  for (int tau = 0; tau < NKT; ++tau) {
    const int d = tau & 1;
    COMPUTE(d);
    // counted wait: drain BDMA(tau+1); keep ISSUE(tau+2) (4 newest) in
    // flight across the barrier. Tail iters drain fully.
    if (tau <= NKT - 4) asm volatile("s_waitcnt vmcnt(4) lgkmcnt(0)" ::: "memory");
    else                asm volatile("s_waitcnt vmcnt(0) lgkmcnt(0)" ::: "memory");
    BAR();
    if (tau + 2 < NKT) {
      BDMA(d, tau + 2);   // independent loads first — fly under CVTW's wait
      CVTW(d);            // compiler inserts counted wait for ra/rc here
    }
    if (tau + 3 < NKT) ISSUE(tau + 3);
    __builtin_amdgcn_sched_barrier(0);
  }
  asm volatile("s_waitcnt vmcnt(0)" ::: "memory");

  // C-write: rhs[(bk*1024 + it*128 + row)][nt*192 + col] bf16
  unsigned short* Cw = rhs + ((size_t)bk * Nn + it * BM) * TF + nt * BN;
#pragma unroll
  for (int mi = 0; mi < 4; ++mi) {
#pragma unroll
    for (int ni = 0; ni < 3; ++ni) {
      const int col = wn * 48 + ni * 16 + lrow;
      const int row0 = wm * 64 + mi * 16 + c0 * 4;
      unsigned short* op = Cw + (size_t)row0 * TF + col;
      f32x4 v = acc[mi][ni];
#pragma unroll
      for (int q = 0; q < 4; ++q)
        op[(size_t)q * TF] = f2bf(v[q]);
    }
  }
}

// ---------------------------------------------------------------------------
// k4: out[b,t,i,o] = relu( sum_{k,f} rhs[b,k,i,t*32+f] * Theta[k,f,o] )
// (UNCHANGED)
// ---------------------------------------------------------------------------
__global__ __launch_bounds__(256) void k4_epilogue(
    const unsigned short* __restrict__ rhs, const float* __restrict__ theta,
    float* __restrict__ out) {
  __shared__ float th[KC * FIN * FOUT];  // 24 KB, [kf][o]
  const int tid = threadIdx.x;
  for (int s = tid; s < KC * FIN * FOUT; s += 256) th[s] = theta[s];
  __syncthreads();
  const int bid = blockIdx.x;            // (b*12 + t)*4 + ic
  const int ic = bid & 3;
  const int bt = bid >> 2;
  const int t = bt % Tt, b = bt / Tt;
  const int w = tid >> 6, l = tid & 63;
  const int lrow = l & 15;
  const int c0 = l >> 4;
  const int i0 = ic * 256 + w * 64;

  short8 bfrag[KC][4];
#pragma unroll
  for (int ks = 0; ks < KC; ++ks)
#pragma unroll
    for (int oi = 0; oi < 4; ++oi) {
      short8 bf;
#pragma unroll
      for (int rr = 0; rr < 8; ++rr)
        bf[rr] = (short)f2bf(th[(ks * FIN + c0 * 8 + rr) * FOUT + oi * 16 + lrow]);
      bfrag[ks][oi] = bf;
    }

  f32x4 acc[4][4];
#pragma unroll
  for (int mi = 0; mi < 4; ++mi)
#pragma unroll
    for (int oi = 0; oi < 4; ++oi)
      acc[mi][oi] = (f32x4){0.f, 0.f, 0.f, 0.f};

#pragma unroll
  for (int ks = 0; ks < KC; ++ks) {
#pragma unroll
    for (int mi = 0; mi < 4; ++mi) {
      const short8 af = *(const short8*)(
          rhs + ((size_t)(b * KC + ks) * Nn + i0 + mi * 16 + lrow) * TF + t * FIN + c0 * 8);
#pragma unroll
      for (int oi = 0; oi < 4; ++oi)
        acc[mi][oi] = __builtin_amdgcn_mfma_f32_16x16x32_bf16(af, bfrag[ks][oi], acc[mi][oi], 0, 0, 0);
    }
  }

#pragma unroll
  for (int mi = 0; mi < 4; ++mi) {
#pragma unroll
    for (int oi = 0; oi < 4; ++oi) {
      const int row = i0 + mi * 16 + c0 * 4;
      float* op = out + ((size_t)(b * Tt + t) * Nn + row) * FOUT + oi * 16 + lrow;
      f32x4 v = acc[mi][oi];
#pragma unroll
      for (int q = 0; q < 4; ++q)
        op[(size_t)q * FOUT] = fmaxf(v[q], 0.f);
    }
  }
}

// ---------------------------------------------------------------------------
// fallback (ws too small): slow but correct, pure f32
// ---------------------------------------------------------------------------
__global__ __launch_bounds__(128) void k_fallback(
    const float* __restrict__ x, const float* __restrict__ att,
    const float* __restrict__ cheb, const float* __restrict__ theta,
    float* __restrict__ out) {
  const int blk = blockIdx.x;  // (b, t, i)
  const int i = blk & 1023;
  const int bt = blk >> 10;
  const int t = bt % Tt, b = bt / Tt;
  __shared__ float rhs[KC * FIN];
  const int tid = threadIdx.x;
  if (tid < KC * FIN) {
    const int k = tid >> 5, f = tid & 31;
    const float* ar = att + ((size_t)b * Nn + i) * Nn;
    const float* cr = cheb + ((size_t)k * Nn + i) * Nn;
    const float* xr = x + ((size_t)(b * Tt + t) * Nn) * FIN + f;
    float s = 0.f;
    for (int j = 0; j < Nn; ++j) s = fmaf(ar[j] * cr[j], xr[(size_t)j * FIN], s);
    rhs[tid] = s;
  }
  __syncthreads();
  if (tid < FOUT) {
    float a = 0.f;
#pragma unroll
    for (int kf = 0; kf < KC * FIN; ++kf) a = fmaf(rhs[kf], theta[kf * FOUT + tid], a);
    out[((size_t)(b * Tt + t) * Nn + i) * FOUT + tid] = fmaxf(a, 0.f);
  }
}

extern "C" void kernel_launch(void* const* d_in, const int* in_sizes, int n_in,
                              void* d_out, int out_size, void* d_ws, size_t ws_size,
                              hipStream_t stream) {
  const float* x     = (const float*)d_in[0];
  const float* att   = (const float*)d_in[1];
  const float* cheb  = (const float*)d_in[2];
  const float* theta = (const float*)d_in[3];
  float* out = (float*)d_out;

  const size_t needYx = (size_t)Bb * TF * Nn * sizeof(unsigned short);      // 12.6 MB
  const size_t needR  = (size_t)Bb * KC * Nn * TF * sizeof(unsigned short); // 37.7 MB
  if (ws_size >= needYx + needR) {
    unsigned short* YxT = (unsigned short*)d_ws;
    unsigned short* rhs = (unsigned short*)((char*)d_ws + needYx);
    hipLaunchKernelGGL(k2r_build_YxT, dim3(Bb * Tt * 4), dim3(256), 0, stream,
                       x, YxT);
    hipLaunchKernelGGL(k3f_gemm, dim3(48 * (Nn / BM) * (TF / BN)), dim3(512), 0, stream,
                       att, cheb, YxT, rhs);
    hipLaunchKernelGGL(k4_epilogue, dim3(Bb * Tt * 4), dim3(256), 0, stream,
                       rhs, theta, out);
  } else {
    hipLaunchKernelGGL(k_fallback, dim3(Bb * Tt * Nn), dim3(128), 0, stream,
                       x, att, cheb, theta, out);
  }
}

// Round 17
// 101.866 us; speedup vs baseline: 2.1598x; 2.1598x over previous
//
#include <hip/hip_runtime.h>

#define Bb 16
#define Tt 12
#define Nn 1024
#define FIN 32
#define FOUT 64
#define KC 3
#define TF (Tt * FIN)    // 384  — (t,f) fused dim
#define NO (Tt * FOUT)   // 768

#define BM 128
#define BN 192
#define BK 32
#define NKT (Nn / BK)    // 32 K-tiles (K = j = 1024)

typedef __attribute__((ext_vector_type(8))) short short8;
typedef __attribute__((ext_vector_type(4))) float f32x4;

__device__ __forceinline__ unsigned short f2bf(float f) {
  union { float f; unsigned u; } v; v.f = f;
  unsigned r = v.u + 0x7FFFu + ((v.u >> 16) & 1u);  // RNE
  return (unsigned short)(r >> 16);
}

__device__ __forceinline__ unsigned cvtpk(float lo, float hi) {
  unsigned r;
  asm("v_cvt_pk_bf16_f32 %0, %1, %2" : "=v"(r) : "v"(lo), "v"(hi));
  return r;
}

__device__ __forceinline__ void BAR() {
  __builtin_amdgcn_sched_barrier(0);
  __builtin_amdgcn_s_barrier();
  __builtin_amdgcn_sched_barrier(0);
}

// ---------------------------------------------------------------------------
// k2r: YxT[b][t*32+f][j] = bf16(x[b,t,j,f]) — LDS-tiled transpose. (UNCHANGED)
// ---------------------------------------------------------------------------
__global__ __launch_bounds__(256) void k2r_build_YxT(
    const float* __restrict__ x, unsigned short* __restrict__ YxT) {
  __shared__ float xs[256][33];   // +1 pad
  const int tid = threadIdx.x;
  const int bid = blockIdx.x;     // (b*12 + t)*4 + jc
  const int jc = bid & 3;
  const int bt = bid >> 2;
  const int t = bt % Tt, b = bt / Tt;
  const int j0 = jc * 256;
  const float* xp = x + ((size_t)(b * Tt + t) * Nn + j0) * FIN;
#pragma unroll
  for (int m = 0; m < 8; ++m) {
    const int flat = m * 256 + tid;        // 0..2047 float4s
    const int j_loc = flat >> 3, f4 = flat & 7;
    const float4 v = *(const float4*)(xp + (size_t)j_loc * FIN + f4 * 4);
    xs[j_loc][f4 * 4 + 0] = v.x; xs[j_loc][f4 * 4 + 1] = v.y;
    xs[j_loc][f4 * 4 + 2] = v.z; xs[j_loc][f4 * 4 + 3] = v.w;
  }
  __syncthreads();
  const int f = tid >> 3, jg = tid & 7;    // 32 f-rows × 8 j-groups
  unsigned short* dst = YxT + ((size_t)b * TF + t * FIN + f) * Nn + j0 + jg * 32;
#pragma unroll
  for (int m = 0; m < 4; ++m) {
    short8 sh;
#pragma unroll
    for (int e = 0; e < 8; ++e)
      sh[e] = (short)f2bf(xs[jg * 32 + m * 8 + e][f]);
    *(short8*)(dst + m * 8) = sh;
  }
}

// ---------------------------------------------------------------------------
// k3f: FUSED A-build + GEMM. R17 = R16 structure with the launch-bounds fix:
// __launch_bounds__(512, 2) — NO compiler VGPR clamp (R16's (512,6) forced
// VGPR=40 and spilled acc -> 400 MB scratch traffic). Occupancy is governed
// by the 48 KB LDS pad: floor(160/48) = 3 blocks/CU exactly, all 768 blocks
// resident in one round (m97's regime — cross-block TLP absorbs barrier
// stalls). BK=32; swizzle key (row>>1)&3 (2-way aliasing = free, m136) on
// all three sites (BDMA source, CVTW write, LDA/LDB read — rule #21).
// Ledger at wait(tau): {BDMA(tau+1)<=2 old, ISSUE(tau+2)=4 new} -> vmcnt(4)
// for tau<=NKT-4; full drain in tail.
// ---------------------------------------------------------------------------
__global__ __launch_bounds__(512, 2) void k3f_gemm(
    const float* __restrict__ att, const float* __restrict__ cheb,
    const unsigned short* __restrict__ YxT, unsigned short* __restrict__ rhs) {
  // used: A 2×4096 + B 2×6144 = 20480 ushorts (40 KB); padded to 48 KB so
  // LDS-occupancy = floor(160/48) = 3 blocks/CU exactly (uniform 3×256=768).
  __shared__ __align__(16) unsigned short lds[24576];
  const int bid = blockIdx.x;
  // 768 blocks; 6 siblings (3kk × 2nt) sharing one (b,it) att panel adjacent
  // on one XCD (R10 grouping, FETCH-verified).
  const int logical = (bid & 7) * 96 + (bid >> 3);   // bijective
  const int g = logical / 6, m = logical % 6;
  const int b  = g >> 3;
  const int it = g & 7;
  const int kk = m >> 1;
  const int nt = m & 1;
  const int bk = b * 3 + kk;
  const float* Aa = att  + ((size_t)b  * Nn + it * BM) * Nn;   // f32 panel
  const float* Ac = cheb + ((size_t)kk * Nn + it * BM) * Nn;   // f32 panel
  const unsigned short* Bp = YxT + ((size_t)b * TF + nt * BN) * Nn;
  const int tid = threadIdx.x;
  const int w = tid >> 6, l = tid & 63;
  const int wm = w >> 2, wn = w & 3;     // 2M × 4N (wave 64×48)
  const int lrow = l & 15;
  const int c0 = l >> 4;                 // k-chunk 0..3 (BK=32 -> 4 chunks)

  f32x4 acc[4][3];
#pragma unroll
  for (int mi = 0; mi < 4; ++mi)
#pragma unroll
    for (int ni = 0; ni < 3; ++ni)
      acc[mi][ni] = (f32x4){0.f, 0.f, 0.f, 0.f};

  float4 ra[2], rc[2];   // single prefetch set (16 VGPR), 1-iter lifetime

  // thread owns row = tid>>2 (0..127), chunk c8 = tid&3 (8 f32 = 32 B)
  const int arow = tid >> 2, ac8 = tid & 3;

  auto ISSUE = [&](int kt) {             // 4 dwordx4 loads -> ra/rc
    const float* ap = Aa + (size_t)arow * Nn + kt * BK + ac8 * 8;
    const float* cp = Ac + (size_t)arow * Nn + kt * BK + ac8 * 8;
    ra[0] = *(const float4*)ap;
    ra[1] = *(const float4*)(ap + 4);
    rc[0] = *(const float4*)cp;
    rc[1] = *(const float4*)(cp + 4);
  };

  auto CVTW = [&](int d) {   // products -> packed bf16 -> one b128 write
    uint4 o;
    o.x = cvtpk(ra[0].x * rc[0].x, ra[0].y * rc[0].y);
    o.y = cvtpk(ra[0].z * rc[0].z, ra[0].w * rc[0].w);
    o.z = cvtpk(ra[1].x * rc[1].x, ra[1].y * rc[1].y);
    o.w = cvtpk(ra[1].z * rc[1].z, ra[1].w * rc[1].w);
    *(uint4*)&lds[d * 4096 + arow * 32 + (ac8 ^ ((arow >> 1) & 3)) * 8] = o;
  };

  auto BDMA = [&](int d, int kt) {       // B: 768 chunks; waves 0-3 do 2nd half
#pragma unroll
    for (int g2 = 0; g2 < 2; ++g2) {
      const int idx = g2 * 512 + tid;    // 0..1023, valid < 768
      if (idx < 768) {
        const int row = idx >> 2;
        const int csrc = (idx & 3) ^ ((row >> 1) & 3);
        __builtin_amdgcn_global_load_lds(
            (const __attribute__((address_space(1))) void*)(Bp + (size_t)row * Nn + kt * BK + csrc * 8),
            (__attribute__((address_space(3))) void*)(lds + 8192 + d * 6144 + (g2 * 512 + w * 64) * 8),
            16, 0, 0);
      }
    }
  };

  auto LDA = [&](int d, int mi) -> short8 {
    const int row = wm * 64 + mi * 16 + lrow;       // 0..127
    const int ch  = c0 ^ ((row >> 1) & 3);
    return *(const short8*)&lds[d * 4096 + row * 32 + ch * 8];
  };
  auto LDB = [&](int d, int ni) -> short8 {
    const int row = wn * 48 + ni * 16 + lrow;       // 0..191
    const int ch  = c0 ^ ((row >> 1) & 3);
    return *(const short8*)&lds[8192 + d * 6144 + row * 32 + ch * 8];
  };

  auto COMPUTE = [&](int d) {
    short8 bf[3];
    __builtin_amdgcn_s_setprio(1);
#pragma unroll
    for (int ni = 0; ni < 3; ++ni) bf[ni] = LDB(d, ni);
#pragma unroll
    for (int mi = 0; mi < 4; ++mi) {
      const short8 af = LDA(d, mi);
#pragma unroll
      for (int ni = 0; ni < 3; ++ni)
        acc[mi][ni] = __builtin_amdgcn_mfma_f32_16x16x32_bf16(af, bf[ni], acc[mi][ni], 0, 0, 0);
    }
    __builtin_amdgcn_s_setprio(0);
  };

  // ---- prologue: A(0),A(1) built; B(0),B(1) DMA'd; ISSUE(2) kept flying ----
  ISSUE(0);
  asm volatile("s_waitcnt vmcnt(0)" ::: "memory");
  CVTW(0);
  ISSUE(1);
  asm volatile("s_waitcnt vmcnt(0)" ::: "memory");
  CVTW(1);
  BDMA(0, 0);
  BDMA(1, 1);
  ISSUE(2);
  asm volatile("s_waitcnt vmcnt(4) lgkmcnt(0)" ::: "memory");  // drain BDMAs+writes, keep ISSUE(2)
  BAR();

  for (int tau = 0; tau < NKT; ++tau) {
    const int d = tau & 1;
    COMPUTE(d);
    // counted wait: drain BDMA(tau+1); keep ISSUE(tau+2) (4 newest) in
    // flight across the barrier. Tail iters drain fully.
    if (tau <= NKT - 4) asm volatile("s_waitcnt vmcnt(4) lgkmcnt(0)" ::: "memory");
    else                asm volatile("s_waitcnt vmcnt(0) lgkmcnt(0)" ::: "memory");
    BAR();
    if (tau + 2 < NKT) {
      BDMA(d, tau + 2);   // independent loads first — fly under CVTW's wait
      CVTW(d);            // compiler inserts counted wait for ra/rc here
    }
    if (tau + 3 < NKT) ISSUE(tau + 3);
    __builtin_amdgcn_sched_barrier(0);
  }
  asm volatile("s_waitcnt vmcnt(0)" ::: "memory");

  // C-write: rhs[(bk*1024 + it*128 + row)][nt*192 + col] bf16
  unsigned short* Cw = rhs + ((size_t)bk * Nn + it * BM) * TF + nt * BN;
#pragma unroll
  for (int mi = 0; mi < 4; ++mi) {
#pragma unroll
    for (int ni = 0; ni < 3; ++ni) {
      const int col = wn * 48 + ni * 16 + lrow;
      const int row0 = wm * 64 + mi * 16 + c0 * 4;
      unsigned short* op = Cw + (size_t)row0 * TF + col;
      f32x4 v = acc[mi][ni];
#pragma unroll
      for (int q = 0; q < 4; ++q)
        op[(size_t)q * TF] = f2bf(v[q]);
    }
  }
}

// ---------------------------------------------------------------------------
// k4: out[b,t,i,o] = relu( sum_{k,f} rhs[b,k,i,t*32+f] * Theta[k,f,o] )
// (UNCHANGED)
// ---------------------------------------------------------------------------
__global__ __launch_bounds__(256) void k4_epilogue(
    const unsigned short* __restrict__ rhs, const float* __restrict__ theta,
    float* __restrict__ out) {
  __shared__ float th[KC * FIN * FOUT];  // 24 KB, [kf][o]
  const int tid = threadIdx.x;
  for (int s = tid; s < KC * FIN * FOUT; s += 256) th[s] = theta[s];
  __syncthreads();
  const int bid = blockIdx.x;            // (b*12 + t)*4 + ic
  const int ic = bid & 3;
  const int bt = bid >> 2;
  const int t = bt % Tt, b = bt / Tt;
  const int w = tid >> 6, l = tid & 63;
  const int lrow = l & 15;
  const int c0 = l >> 4;
  const int i0 = ic * 256 + w * 64;

  short8 bfrag[KC][4];
#pragma unroll
  for (int ks = 0; ks < KC; ++ks)
#pragma unroll
    for (int oi = 0; oi < 4; ++oi) {
      short8 bf;
#pragma unroll
      for (int rr = 0; rr < 8; ++rr)
        bf[rr] = (short)f2bf(th[(ks * FIN + c0 * 8 + rr) * FOUT + oi * 16 + lrow]);
      bfrag[ks][oi] = bf;
    }

  f32x4 acc[4][4];
#pragma unroll
  for (int mi = 0; mi < 4; ++mi)
#pragma unroll
    for (int oi = 0; oi < 4; ++oi)
      acc[mi][oi] = (f32x4){0.f, 0.f, 0.f, 0.f};

#pragma unroll
  for (int ks = 0; ks < KC; ++ks) {
#pragma unroll
    for (int mi = 0; mi < 4; ++mi) {
      const short8 af = *(const short8*)(
          rhs + ((size_t)(b * KC + ks) * Nn + i0 + mi * 16 + lrow) * TF + t * FIN + c0 * 8);
#pragma unroll
      for (int oi = 0; oi < 4; ++oi)
        acc[mi][oi] = __builtin_amdgcn_mfma_f32_16x16x32_bf16(af, bfrag[ks][oi], acc[mi][oi], 0, 0, 0);
    }
  }

#pragma unroll
  for (int mi = 0; mi < 4; ++mi) {
#pragma unroll
    for (int oi = 0; oi < 4; ++oi) {
      const int row = i0 + mi * 16 + c0 * 4;
      float* op = out + ((size_t)(b * Tt + t) * Nn + row) * FOUT + oi * 16 + lrow;
      f32x4 v = acc[mi][oi];
#pragma unroll
      for (int q = 0; q < 4; ++q)
        op[(size_t)q * FOUT] = fmaxf(v[q], 0.f);
    }
  }
}

// ---------------------------------------------------------------------------
// fallback (ws too small): slow but correct, pure f32
// ---------------------------------------------------------------------------
__global__ __launch_bounds__(128) void k_fallback(
    const float* __restrict__ x, const float* __restrict__ att,
    const float* __restrict__ cheb, const float* __restrict__ theta,
    float* __restrict__ out) {
  const int blk = blockIdx.x;  // (b, t, i)
  const int i = blk & 1023;
  const int bt = blk >> 10;
  const int t = bt % Tt, b = bt / Tt;
  __shared__ float rhs[KC * FIN];
  const int tid = threadIdx.x;
  if (tid < KC * FIN) {
    const int k = tid >> 5, f = tid & 31;
    const float* ar = att + ((size_t)b * Nn + i) * Nn;
    const float* cr = cheb + ((size_t)k * Nn + i) * Nn;
    const float* xr = x + ((size_t)(b * Tt + t) * Nn) * FIN + f;
    float s = 0.f;
    for (int j = 0; j < Nn; ++j) s = fmaf(ar[j] * cr[j], xr[(size_t)j * FIN], s);
    rhs[tid] = s;
  }
  __syncthreads();
  if (tid < FOUT) {
    float a = 0.f;
#pragma unroll
    for (int kf = 0; kf < KC * FIN; ++kf) a = fmaf(rhs[kf], theta[kf * FOUT + tid], a);
    out[((size_t)(b * Tt + t) * Nn + i) * FOUT + tid] = fmaxf(a, 0.f);
  }
}

extern "C" void kernel_launch(void* const* d_in, const int* in_sizes, int n_in,
                              void* d_out, int out_size, void* d_ws, size_t ws_size,
                              hipStream_t stream) {
  const float* x     = (const float*)d_in[0];
  const float* att   = (const float*)d_in[1];
  const float* cheb  = (const float*)d_in[2];
  const float* theta = (const float*)d_in[3];
  float* out = (float*)d_out;

  const size_t needYx = (size_t)Bb * TF * Nn * sizeof(unsigned short);      // 12.6 MB
  const size_t needR  = (size_t)Bb * KC * Nn * TF * sizeof(unsigned short); // 37.7 MB
  if (ws_size >= needYx + needR) {
    unsigned short* YxT = (unsigned short*)d_ws;
    unsigned short* rhs = (unsigned short*)((char*)d_ws + needYx);
    hipLaunchKernelGGL(k2r_build_YxT, dim3(Bb * Tt * 4), dim3(256), 0, stream,
                       x, YxT);
    hipLaunchKernelGGL(k3f_gemm, dim3(48 * (Nn / BM) * (TF / BN)), dim3(512), 0, stream,
                       att, cheb, YxT, rhs);
    hipLaunchKernelGGL(k4_epilogue, dim3(Bb * Tt * 4), dim3(256), 0, stream,
                       rhs, theta, out);
  } else {
    hipLaunchKernelGGL(k_fallback, dim3(Bb * Tt * Nn), dim3(128), 0, stream,
                       x, att, cheb, theta, out);
  }
}

// Round 18
// 100.882 us; speedup vs baseline: 2.1809x; 1.0098x over previous
//
#include <hip/hip_runtime.h>

#define Bb 16
#define Tt 12
#define Nn 1024
#define FIN 32
#define FOUT 64
#define KC 3
#define TF (Tt * FIN)    // 384  — (t,f) fused dim
#define NO (Tt * FOUT)   // 768

#define BM 128
#define BN 192
#define BK 64
#define NKT (Nn / BK)    // 16 K-tiles (K = j = 1024)

typedef __attribute__((ext_vector_type(8))) short short8;
typedef __attribute__((ext_vector_type(4))) float f32x4;

__device__ __forceinline__ unsigned short f2bf(float f) {
  union { float f; unsigned u; } v; v.f = f;
  unsigned r = v.u + 0x7FFFu + ((v.u >> 16) & 1u);  // RNE
  return (unsigned short)(r >> 16);
}

__device__ __forceinline__ void BAR() {
  __builtin_amdgcn_sched_barrier(0);
  __builtin_amdgcn_s_barrier();
  __builtin_amdgcn_sched_barrier(0);
}

// ---------------------------------------------------------------------------
// k2r: YxT[b][t*32+f][j] = bf16(x[b,t,j,f]) — LDS-tiled transpose.
// ---------------------------------------------------------------------------
__global__ __launch_bounds__(256) void k2r_build_YxT(
    const float* __restrict__ x, unsigned short* __restrict__ YxT) {
  __shared__ float xs[256][33];   // +1 pad
  const int tid = threadIdx.x;
  const int bid = blockIdx.x;     // (b*12 + t)*4 + jc
  const int jc = bid & 3;
  const int bt = bid >> 2;
  const int t = bt % Tt, b = bt / Tt;
  const int j0 = jc * 256;
  const float* xp = x + ((size_t)(b * Tt + t) * Nn + j0) * FIN;
#pragma unroll
  for (int m = 0; m < 8; ++m) {
    const int flat = m * 256 + tid;        // 0..2047 float4s
    const int j_loc = flat >> 3, f4 = flat & 7;
    const float4 v = *(const float4*)(xp + (size_t)j_loc * FIN + f4 * 4);
    xs[j_loc][f4 * 4 + 0] = v.x; xs[j_loc][f4 * 4 + 1] = v.y;
    xs[j_loc][f4 * 4 + 2] = v.z; xs[j_loc][f4 * 4 + 3] = v.w;
  }
  __syncthreads();
  const int f = tid >> 3, jg = tid & 7;    // 32 f-rows × 8 j-groups
  unsigned short* dst = YxT + ((size_t)b * TF + t * FIN + f) * Nn + j0 + jg * 32;
#pragma unroll
  for (int m = 0; m < 4; ++m) {
    short8 sh;
#pragma unroll
    for (int e = 0; e < 8; ++e)
      sh[e] = (short)f2bf(xs[jg * 32 + m * 8 + e][f]);
    *(short8*)(dst + m * 8) = sh;
  }
}

// ---------------------------------------------------------------------------
// k3f: FUSED A-build + GEMM — the session's best-measured configuration
// (R14): BK=64, 80 KB LDS, 2 blocks/CU, single barrier/tile, counted
// vmcnt(8) (drains BDMA(tau+1), keeps ISSUE(tau+2)'s 8 f32 loads in flight
// across the barrier; consumer CVTW gets a compiler counted wait covered by
// a full COMPUTE). Swizzle involution c^(row&7) on all three sites.
// ---------------------------------------------------------------------------
__global__ __launch_bounds__(512, 4) void k3f_gemm(
    const float* __restrict__ att, const float* __restrict__ cheb,
    const unsigned short* __restrict__ YxT, unsigned short* __restrict__ rhs) {
  __shared__ __align__(16) unsigned short lds[40960];  // A 2×16KB, B 2×24KB
  const int bid = blockIdx.x;
  // 768 blocks; 6 siblings (3kk × 2nt) sharing one (b,it) att panel adjacent
  // on one XCD (R10 grouping, FETCH-verified).
  const int logical = (bid & 7) * 96 + (bid >> 3);   // bijective
  const int g = logical / 6, m = logical % 6;
  const int b  = g >> 3;
  const int it = g & 7;
  const int kk = m >> 1;
  const int nt = m & 1;
  const int bk = b * 3 + kk;
  const float* Aa = att  + ((size_t)b  * Nn + it * BM) * Nn;   // f32 panel
  const float* Ac = cheb + ((size_t)kk * Nn + it * BM) * Nn;   // f32 panel
  const unsigned short* Bp = YxT + ((size_t)b * TF + nt * BN) * Nn;
  const int tid = threadIdx.x;
  const int w = tid >> 6, l = tid & 63;
  const int wm = w >> 2, wn = w & 3;     // 2M × 4N (wave 64×48)
  const int lrow = l & 15;
  const int c0 = l >> 4;
  const int sx = lrow & 7;

  f32x4 acc[4][3];
#pragma unroll
  for (int mi = 0; mi < 4; ++mi)
#pragma unroll
    for (int ni = 0; ni < 3; ++ni)
      acc[mi][ni] = (f32x4){0.f, 0.f, 0.f, 0.f};

  float4 ra[4], rc[4];   // single prefetch set (32 VGPR), 1-iter lifetime

  auto ISSUE = [&](int kt) {             // issue 8 dwordx4 loads -> ra/rc
#pragma unroll
    for (int u = 0; u < 2; ++u) {
      const int idx = u * 512 + tid;     // 0..1023 = row*8 + c
      const int row = idx >> 3, c = idx & 7;
      const float* ap = Aa + (size_t)row * Nn + kt * BK + c * 8;
      const float* cp = Ac + (size_t)row * Nn + kt * BK + c * 8;
      ra[2 * u]     = *(const float4*)ap;
      ra[2 * u + 1] = *(const float4*)(ap + 4);
      rc[2 * u]     = *(const float4*)cp;
      rc[2 * u + 1] = *(const float4*)(cp + 4);
    }
  };

  auto CVTW = [&](int d) {               // products -> bf16 -> swizzled ds_write
#pragma unroll
    for (int u = 0; u < 2; ++u) {
      const int idx = u * 512 + tid;
      const int row = idx >> 3, c = idx & 7;
      short8 o;
      o[0] = (short)f2bf(ra[2 * u].x * rc[2 * u].x);
      o[1] = (short)f2bf(ra[2 * u].y * rc[2 * u].y);
      o[2] = (short)f2bf(ra[2 * u].z * rc[2 * u].z);
      o[3] = (short)f2bf(ra[2 * u].w * rc[2 * u].w);
      o[4] = (short)f2bf(ra[2 * u + 1].x * rc[2 * u + 1].x);
      o[5] = (short)f2bf(ra[2 * u + 1].y * rc[2 * u + 1].y);
      o[6] = (short)f2bf(ra[2 * u + 1].z * rc[2 * u + 1].z);
      o[7] = (short)f2bf(ra[2 * u + 1].w * rc[2 * u + 1].w);
      *(short8*)&lds[d * 8192 + row * 64 + (c ^ (row & 7)) * 8] = o;
    }
  };

  auto BDMA = [&](int d, int kt) {       // B via global_load_lds
#pragma unroll
    for (int g2 = 0; g2 < 3; ++g2) {
      const int idx = g2 * 512 + tid;    // 0..1535
      const int row = idx >> 3;
      const int csrc = (idx & 7) ^ (row & 7);
      __builtin_amdgcn_global_load_lds(
          (const __attribute__((address_space(1))) void*)(Bp + (size_t)row * Nn + kt * BK + csrc * 8),
          (__attribute__((address_space(3))) void*)(lds + 16384 + d * 12288 + (g2 * 512 + w * 64) * 8),
          16, 0, 0);
    }
  };

  auto LDA = [&](int d, int mi, int ks) -> short8 {
    const int row = wm * 64 + mi * 16 + lrow;       // 0..127
    const int ch  = (c0 | (ks << 2)) ^ sx;
    return *(const short8*)&lds[d * 8192 + row * 64 + ch * 8];
  };
  auto LDB = [&](int d, int ni, int ks) -> short8 {
    const int row = wn * 48 + ni * 16 + lrow;       // 0..191
    const int ch  = (c0 | (ks << 2)) ^ sx;
    return *(const short8*)&lds[16384 + d * 12288 + row * 64 + ch * 8];
  };

  auto COMPUTE = [&](int d) {
    short8 bf[3];
    __builtin_amdgcn_s_setprio(1);
#pragma unroll
    for (int ni = 0; ni < 3; ++ni) bf[ni] = LDB(d, ni, 0);
#pragma unroll
    for (int mi = 0; mi < 4; ++mi) {
      const short8 af = LDA(d, mi, 0);
#pragma unroll
      for (int ni = 0; ni < 3; ++ni)
        acc[mi][ni] = __builtin_amdgcn_mfma_f32_16x16x32_bf16(af, bf[ni], acc[mi][ni], 0, 0, 0);
    }
#pragma unroll
    for (int ni = 0; ni < 3; ++ni) bf[ni] = LDB(d, ni, 1);
#pragma unroll
    for (int mi = 0; mi < 4; ++mi) {
      const short8 af = LDA(d, mi, 1);
#pragma unroll
      for (int ni = 0; ni < 3; ++ni)
        acc[mi][ni] = __builtin_amdgcn_mfma_f32_16x16x32_bf16(af, bf[ni], acc[mi][ni], 0, 0, 0);
    }
    __builtin_amdgcn_s_setprio(0);
  };

  // ---- prologue: A(0),A(1) built; B(0),B(1) DMA'd; ISSUE(2) kept flying ----
  ISSUE(0);
  asm volatile("s_waitcnt vmcnt(0)" ::: "memory");
  CVTW(0);
  ISSUE(1);
  asm volatile("s_waitcnt vmcnt(0)" ::: "memory");
  CVTW(1);
  BDMA(0, 0);
  BDMA(1, 1);
  ISSUE(2);
  asm volatile("s_waitcnt vmcnt(8) lgkmcnt(0)" ::: "memory");  // drain BDMAs+writes, keep ISSUE(2)
  BAR();

  for (int tau = 0; tau < NKT; ++tau) {
    const int d = tau & 1;
    COMPUTE(d);
    // counted wait: drain BDMA(tau+1) (3 oldest); keep ISSUE(tau+2) (8 newest)
    // in flight across the barrier. Tail iters drain fully.
    if (tau <= NKT - 4) asm volatile("s_waitcnt vmcnt(8) lgkmcnt(0)" ::: "memory");
    else                asm volatile("s_waitcnt vmcnt(0) lgkmcnt(0)" ::: "memory");
    BAR();
    if (tau + 2 < NKT) {
      BDMA(d, tau + 2);   // independent loads first — fly under CVTW's wait
      CVTW(d);            // compiler inserts counted wait for ra/rc here
    }
    if (tau + 3 < NKT) ISSUE(tau + 3);
    __builtin_amdgcn_sched_barrier(0);
  }
  asm volatile("s_waitcnt vmcnt(0)" ::: "memory");

  // C-write: rhs[(bk*1024 + it*128 + row)][nt*192 + col] bf16
  unsigned short* Cw = rhs + ((size_t)bk * Nn + it * BM) * TF + nt * BN;
#pragma unroll
  for (int mi = 0; mi < 4; ++mi) {
#pragma unroll
    for (int ni = 0; ni < 3; ++ni) {
      const int col = wn * 48 + ni * 16 + lrow;
      const int row0 = wm * 64 + mi * 16 + c0 * 4;
      unsigned short* op = Cw + (size_t)row0 * TF + col;
      f32x4 v = acc[mi][ni];
#pragma unroll
      for (int q = 0; q < 4; ++q)
        op[(size_t)q * TF] = f2bf(v[q]);
    }
  }
}

// ---------------------------------------------------------------------------
// k4: out[b,t,i,o] = relu( sum_{k,f} rhs[b,k,i,t*32+f] * Theta[k,f,o] )
// ---------------------------------------------------------------------------
__global__ __launch_bounds__(256) void k4_epilogue(
    const unsigned short* __restrict__ rhs, const float* __restrict__ theta,
    float* __restrict__ out) {
  __shared__ float th[KC * FIN * FOUT];  // 24 KB, [kf][o]
  const int tid = threadIdx.x;
  for (int s = tid; s < KC * FIN * FOUT; s += 256) th[s] = theta[s];
  __syncthreads();
  const int bid = blockIdx.x;            // (b*12 + t)*4 + ic
  const int ic = bid & 3;
  const int bt = bid >> 2;
  const int t = bt % Tt, b = bt / Tt;
  const int w = tid >> 6, l = tid & 63;
  const int lrow = l & 15;
  const int c0 = l >> 4;
  const int i0 = ic * 256 + w * 64;

  short8 bfrag[KC][4];
#pragma unroll
  for (int ks = 0; ks < KC; ++ks)
#pragma unroll
    for (int oi = 0; oi < 4; ++oi) {
      short8 bf;
#pragma unroll
      for (int rr = 0; rr < 8; ++rr)
        bf[rr] = (short)f2bf(th[(ks * FIN + c0 * 8 + rr) * FOUT + oi * 16 + lrow]);
      bfrag[ks][oi] = bf;
    }

  f32x4 acc[4][4];
#pragma unroll
  for (int mi = 0; mi < 4; ++mi)
#pragma unroll
    for (int oi = 0; oi < 4; ++oi)
      acc[mi][oi] = (f32x4){0.f, 0.f, 0.f, 0.f};

#pragma unroll
  for (int ks = 0; ks < KC; ++ks) {
#pragma unroll
    for (int mi = 0; mi < 4; ++mi) {
      const short8 af = *(const short8*)(
          rhs + ((size_t)(b * KC + ks) * Nn + i0 + mi * 16 + lrow) * TF + t * FIN + c0 * 8);
#pragma unroll
      for (int oi = 0; oi < 4; ++oi)
        acc[mi][oi] = __builtin_amdgcn_mfma_f32_16x16x32_bf16(af, bfrag[ks][oi], acc[mi][oi], 0, 0, 0);
    }
  }

#pragma unroll
  for (int mi = 0; mi < 4; ++mi) {
#pragma unroll
    for (int oi = 0; oi < 4; ++oi) {
      const int row = i0 + mi * 16 + c0 * 4;
      float* op = out + ((size_t)(b * Tt + t) * Nn + row) * FOUT + oi * 16 + lrow;
      f32x4 v = acc[mi][oi];
#pragma unroll
      for (int q = 0; q < 4; ++q)
        op[(size_t)q * FOUT] = fmaxf(v[q], 0.f);
    }
  }
}

// ---------------------------------------------------------------------------
// fallback (ws too small): slow but correct, pure f32
// ---------------------------------------------------------------------------
__global__ __launch_bounds__(128) void k_fallback(
    const float* __restrict__ x, const float* __restrict__ att,
    const float* __restrict__ cheb, const float* __restrict__ theta,
    float* __restrict__ out) {
  const int blk = blockIdx.x;  // (b, t, i)
  const int i = blk & 1023;
  const int bt = blk >> 10;
  const int t = bt % Tt, b = bt / Tt;
  __shared__ float rhs[KC * FIN];
  const int tid = threadIdx.x;
  if (tid < KC * FIN) {
    const int k = tid >> 5, f = tid & 31;
    const float* ar = att + ((size_t)b * Nn + i) * Nn;
    const float* cr = cheb + ((size_t)k * Nn + i) * Nn;
    const float* xr = x + ((size_t)(b * Tt + t) * Nn) * FIN + f;
    float s = 0.f;
    for (int j = 0; j < Nn; ++j) s = fmaf(ar[j] * cr[j], xr[(size_t)j * FIN], s);
    rhs[tid] = s;
  }
  __syncthreads();
  if (tid < FOUT) {
    float a = 0.f;
#pragma unroll
    for (int kf = 0; kf < KC * FIN; ++kf) a = fmaf(rhs[kf], theta[kf * FOUT + tid], a);
    out[((size_t)(b * Tt + t) * Nn + i) * FOUT + tid] = fmaxf(a, 0.f);
  }
}

extern "C" void kernel_launch(void* const* d_in, const int* in_sizes, int n_in,
                              void* d_out, int out_size, void* d_ws, size_t ws_size,
                              hipStream_t stream) {
  const float* x     = (const float*)d_in[0];
  const float* att   = (const float*)d_in[1];
  const float* cheb  = (const float*)d_in[2];
  const float* theta = (const float*)d_in[3];
  float* out = (float*)d_out;

  const size_t needYx = (size_t)Bb * TF * Nn * sizeof(unsigned short);      // 12.6 MB
  const size_t needR  = (size_t)Bb * KC * Nn * TF * sizeof(unsigned short); // 37.7 MB
  if (ws_size >= needYx + needR) {
    unsigned short* YxT = (unsigned short*)d_ws;
    unsigned short* rhs = (unsigned short*)((char*)d_ws + needYx);
    hipLaunchKernelGGL(k2r_build_YxT, dim3(Bb * Tt * 4), dim3(256), 0, stream,
                       x, YxT);
    hipLaunchKernelGGL(k3f_gemm, dim3(48 * (Nn / BM) * (TF / BN)), dim3(512), 0, stream,
                       att, cheb, YxT, rhs);
    hipLaunchKernelGGL(k4_epilogue, dim3(Bb * Tt * 4), dim3(256), 0, stream,
                       rhs, theta, out);
  } else {
    hipLaunchKernelGGL(k_fallback, dim3(Bb * Tt * Nn), dim3(128), 0, stream,
                       x, att, cheb, theta, out);
  }
}